// Round 9
// baseline (347.723 us; speedup 1.0000x reference)
//
#include <hip/hip_runtime.h>
#include <hip/hip_bf16.h>

// Block-sparse FFN via compacted-weight MFMA, v9 (1024-thread block, 16 waves).
//   out = gelu(x @ (W1*M1)^T + b1) @ (W2*M2)^T + b2
// Prep: count -> scan -> gather. Contiguous per-group weight/idx streams in wave
// order, slots padded to x16 (zero weight tiles), idx tail margins zeroed.
// Main: 32 x-rows/block, 1024 thr (16 waves), 148.5 KB LDS, 1 blk/CU but
// 4 waves/SIMD. Window = 8 slots: 2 B-tiles x 2 row-halves = 4 MFMAs; pair-window
// loop = 2-deep prefetch, running pointers. Coalesced float4 epilogue via LDS.

typedef __attribute__((ext_vector_type(8))) short short8;
typedef __attribute__((ext_vector_type(4))) float f32x4;
typedef unsigned long long u64;
typedef unsigned short ushort_t;

#define DIM 768
#define FF 3072
#define NF16 192            // FF/16
#define ND16 48             // DIM/16
#define NDB 96              // DIM/8
#define NFB 384             // FF/8
#define MR 32               // x rows per block
#define NT 1024             // threads per block (16 waves)
#define XP 776              // xs pitch (bf16 elems), row stride 1552 B
#define HP 1544             // hs pitch (bf16 elems), row stride 3088 B
#define XSEC (16 * XP)      // elem offset of x rows 16..31
#define HSEC (16 * HP)      // elem offset of h rows 16..31

#define S1CAP (NF16 * 96 + 32)       // + tail margin for prefetch overrun
#define S2CAP (ND16 * 2 * 192 + 32)
#define W1S_TOT (S1CAP * 128)
#define W2S_TOT (S2CAP * 128)

#define MFMA __builtin_amdgcn_mfma_f32_16x16x32_bf16

__device__ __forceinline__ float gelu_fast(float v) {
    // x * sigmoid(1.5957691x + 0.07135548x^3) via exp2:
    // t2 = -log2(e)*(1.5957691v + 0.07135548v^3)
    float t2 = v * fmaf(v * v, -0.10295667f, -2.30235629f);
    return v / (1.0f + exp2f(t2));
}
__device__ __forceinline__ ushort_t f2bs(float f) {
    union { __hip_bfloat16 h; ushort_t u; } cv;
    cv.h = __float2bfloat16(f);
    return cv.u;
}

// ---------------- prep 1: per-group padded counts ----------------
__global__ __launch_bounds__(64)
void prep_count(const int* __restrict__ mask1, const int* __restrict__ mask2,
                int* __restrict__ off1, int* __restrict__ off2)
{
    const int l = threadIdx.x;
    const int g = blockIdx.x;
    if (g < NF16) {
        const int* r0 = mask1 + (2 * g) * NDB;
        const int* r1 = r0 + NDB;
        bool ua = (r0[l] | r1[l]) != 0;
        u64 ba = __ballot(ua);
        bool ub = (l < 32) && ((r0[64 + l] | r1[64 + l]) != 0);
        u64 bb = __ballot(ub);
        if (l == 0) {
            int cnt = __popcll(ba) + __popcll(bb);
            off1[g + 1] = (cnt + 15) & ~15;
        }
    } else {
        const int G = g - NF16;
        const int* r0 = mask2 + (2 * G) * NFB;
        const int* r1 = r0 + NFB;
        int c0 = 0, c1 = 0;
        #pragma unroll
        for (int p = 0; p < 6; ++p) {
            u64 b = __ballot((r0[p * 64 + l] | r1[p * 64 + l]) != 0);
            if (p < 3) c0 += __popcll(b); else c1 += __popcll(b);
        }
        if (l == 0) {
            off2[0 * ND16 + G + 1] = (c0 + 15) & ~15;
            off2[1 * ND16 + G + 1] = (c1 + 15) & ~15;
        }
    }
}

// ---------------- prep 2: serial prefix scan + zero idx tail margins ----------------
__global__ __launch_bounds__(64)
void prep_scan(int* __restrict__ off1, int* __restrict__ off2,
               ushort_t* __restrict__ idx1s, ushort_t* __restrict__ idx2s)
{
    if (threadIdx.x == 0) {
        off1[0] = 0;
        for (int i = 0; i < NF16; ++i) off1[i + 1] += off1[i];
        int e = off1[NF16];
        for (int i = 0; i < 32; ++i) idx1s[e + i] = 0;   // safe prefetch overrun
    } else if (threadIdx.x == 1) {
        off2[0] = 0;
        for (int i = 0; i < 2 * ND16; ++i) off2[i + 1] += off2[i];
        int e = off2[2 * ND16];
        for (int i = 0; i < 32; ++i) idx2s[e + i] = 0;
    }
}

// ---------------- prep 3: gather compacted weights + indices ----------------
__global__ __launch_bounds__(256)
void prep_gather(const float* __restrict__ W1, const float* __restrict__ W2,
                 const int* __restrict__ mask1, const int* __restrict__ mask2,
                 const int* __restrict__ off1, const int* __restrict__ off2,
                 __hip_bfloat16* __restrict__ w1s, __hip_bfloat16* __restrict__ w2s,
                 ushort_t* __restrict__ idx1s, ushort_t* __restrict__ idx2s)
{
    __shared__ ushort_t sidx[192];
    __shared__ int sc[1];
    const int tid = threadIdx.x;
    const int l = tid & 63;
    const int g = blockIdx.x;

    if (g < NF16) {                       // ---- fc1 group F ----
        const int F = g;
        const int* r0 = mask1 + (2 * F) * NDB;
        const int* r1 = r0 + NDB;
        if (tid < 64) {
            bool ua = (r0[l] | r1[l]) != 0;
            u64 ba = __ballot(ua);
            bool ub = (l < 32) && ((r0[64 + l] | r1[64 + l]) != 0);
            u64 bb = __ballot(ub);
            int ca = __popcll(ba);
            if (ua) sidx[__popcll(ba & ((1ull << l) - 1ull))] = (ushort_t)l;
            if (ub) sidx[ca + __popcll(bb & ((1ull << l) - 1ull))] = (ushort_t)(64 + l);
            int cnt = ca + __popcll(bb);
            if (l == 0) {
                sc[0] = cnt;
                int cntp = (cnt + 15) & ~15;
                for (int i = cnt; i < cntp && i < 192; ++i) sidx[i] = 0;
            }
        }
        __syncthreads();
        const int cnt = sc[0];
        const int base = off1[F];
        const int cntp = off1[F + 1] - base;
        if (tid < cntp) idx1s[base + tid] = sidx[tid];
        for (int e = tid; e < cntp * 128; e += 256) {
            int slot = e >> 7, r = (e >> 3) & 15, j = e & 7;
            int db = sidx[slot];
            float w = 0.f;
            if (slot < cnt && mask1[(2 * F + (r >> 3)) * NDB + db])
                w = W1[(long)(F * 16 + r) * DIM + db * 8 + j];
            w1s[(long)base * 128 + e] = __float2bfloat16(w);
        }
    } else {                              // ---- fc2 (chunk, G) ----
        const int gi = g - NF16;
        const int c = gi / ND16;
        const int G = gi % ND16;
        const int* r0 = mask2 + (2 * G) * NFB;
        const int* r1 = r0 + NFB;
        if (tid < 64) {
            u64 b[3]; int pc[3];
            #pragma unroll
            for (int p = 0; p < 3; ++p) {
                int fb = c * 192 + p * 64 + l;
                b[p] = __ballot((r0[fb] | r1[fb]) != 0);
                pc[p] = __popcll(b[p]);
            }
            int basea = 0;
            #pragma unroll
            for (int p = 0; p < 3; ++p) {
                if ((b[p] >> l) & 1ull)
                    sidx[basea + __popcll(b[p] & ((1ull << l) - 1ull))] = (ushort_t)(p * 64 + l);
                basea += pc[p];
            }
            if (l == 0) {
                int cnt = basea;
                sc[0] = cnt;
                int cntp = (cnt + 15) & ~15;
                for (int i = cnt; i < cntp && i < 192; ++i) sidx[i] = 0;
            }
        }
        __syncthreads();
        const int cnt = sc[0];
        const int base = off2[c * ND16 + G];
        const int cntp = off2[c * ND16 + G + 1] - base;
        if (tid < cntp) idx2s[base + tid] = sidx[tid];
        for (int e = tid; e < cntp * 128; e += 256) {
            int slot = e >> 7, r = (e >> 3) & 15, j = e & 7;
            int lfb = sidx[slot];                 // chunk-local fb (0..191)
            int fb = c * 192 + lfb;
            float w = 0.f;
            if (slot < cnt && mask2[(2 * G + (r >> 3)) * NFB + fb])
                w = W2[(long)(G * 16 + r) * FF + fb * 8 + j];
            w2s[(long)base * 128 + e] = __float2bfloat16(w);
        }
    }
}

// ---------------- main fused kernel ----------------
#define PREF(BUF, IP, WP, ARR, ROWOFF, SECOFF)                          \
    {                                                                   \
        uint4 q = *(const uint4*)(IP);                                  \
        unsigned dd0 = (lg & 2) ? q.y : q.x;                            \
        unsigned dd1 = (lg & 2) ? q.w : q.z;                            \
        int mo0 = (int)((dd0 >> shsel) & 0xffffu) * 8;                  \
        int mo1 = (int)((dd1 >> shsel) & 0xffffu) * 8;                  \
        BUF##a0 = *(const short8*)&ARR[ROWOFF + mo0];                   \
        BUF##a1 = *(const short8*)&ARR[ROWOFF + SECOFF + mo0];          \
        BUF##a2 = *(const short8*)&ARR[ROWOFF + mo1];                   \
        BUF##a3 = *(const short8*)&ARR[ROWOFF + SECOFF + mo1];          \
        BUF##w0 = *(const short8*)(WP);                                 \
        BUF##w1 = *(const short8*)(WP + 512);                           \
    }

#define PAIRSTEP(IP, WP, ARR, ROWOFF, SECOFF)                           \
    {                                                                   \
        short8 t0 = Aa0, t1 = Aa1, t2 = Aa2, t3 = Aa3, u0 = Aw0, u1 = Aw1; \
        PREF(A, IP, WP, ARR, ROWOFF, SECOFF)                            \
        ca = MFMA(t0, u0, ca, 0, 0, 0); cc = MFMA(t1, u0, cc, 0, 0, 0); \
        cb = MFMA(t2, u1, cb, 0, 0, 0); cd = MFMA(t3, u1, cd, 0, 0, 0); \
    }                                                                   \
    {                                                                   \
        short8 t0 = Ba0, t1 = Ba1, t2 = Ba2, t3 = Ba3, u0 = Bw0, u1 = Bw1; \
        PREF(B, (IP + 8), (WP + 1024), ARR, ROWOFF, SECOFF)             \
        ca = MFMA(t0, u0, ca, 0, 0, 0); cc = MFMA(t1, u0, cc, 0, 0, 0); \
        cb = MFMA(t2, u1, cb, 0, 0, 0); cd = MFMA(t3, u1, cd, 0, 0, 0); \
    }                                                                   \
    IP += 16; WP += 2048; s += 16;

__global__ __launch_bounds__(NT, 4)
void bsffn_main(const float* __restrict__ x,
                const float* __restrict__ pb1, const float* __restrict__ pb2,
                const ushort_t* __restrict__ w1s, const ushort_t* __restrict__ w2s,
                const ushort_t* __restrict__ idx1s, const ushort_t* __restrict__ idx2s,
                const int* __restrict__ off1, const int* __restrict__ off2,
                float* __restrict__ out)
{
    __shared__ __align__(16) ushort_t xs[MR * XP];   // 49,664 B
    __shared__ __align__(16) ushort_t hs[MR * HP];   // 98,816 B (reused as f32 sacc)

    const int tid = threadIdx.x;
    const int wave = tid >> 6;                 // 0..15
    const int l = tid & 63;
    const int l15 = l & 15;
    const int lg = l >> 4;
    const int xrow = l15 * XP;
    const int hrow = l15 * HP;
    const int lofs = lg * 128 + l15 * 8;
    const unsigned shsel = (unsigned)((lg & 1) << 4);
    const long rowBase = (long)blockIdx.x * MR;

    // ---- stage x tile -> bf16 LDS ----
    {
        const float* xr = x + rowBase * DIM;
        #pragma unroll
        for (int i = 0; i < 3; ++i) {
            int e = tid + i * NT;              // 32 rows x 96 col-groups(8)
            int row = e / 96, c8 = e % 96;
            const float4 v0 = *(const float4*)(xr + row * DIM + c8 * 8);
            const float4 v1 = *(const float4*)(xr + row * DIM + c8 * 8 + 4);
            uint4 wv;
            wv.x = (unsigned)f2bs(v0.x) | ((unsigned)f2bs(v0.y) << 16);
            wv.y = (unsigned)f2bs(v0.z) | ((unsigned)f2bs(v0.w) << 16);
            wv.z = (unsigned)f2bs(v1.x) | ((unsigned)f2bs(v1.y) << 16);
            wv.w = (unsigned)f2bs(v1.z) | ((unsigned)f2bs(v1.w) << 16);
            *(uint4*)&xs[row * XP + c8 * 8] = wv;
        }
    }

    f32x4 acc0[3], acc1[3];
    #pragma unroll
    for (int t = 0; t < 3; ++t) {
        acc0[t] = (f32x4){0.f, 0.f, 0.f, 0.f};
        acc1[t] = (f32x4){0.f, 0.f, 0.f, 0.f};
    }

    __syncthreads();

    for (int chunk = 0; chunk < 2; ++chunk) {
        // ---------- fc1: linear stream over the wave's 6 groups ----------
        {
            const int Fbeg = chunk * 96 + wave * 6;
            int s = off1[Fbeg];
            const ushort_t* ip = idx1s + s;
            const ushort_t* wp = w1s + (long)s * 128 + lofs;
            short8 Aa0, Aa1, Aa2, Aa3, Aw0, Aw1, Ba0, Ba1, Ba2, Ba3, Bw0, Bw1;
            PREF(A, ip, wp, xs, xrow, XSEC)
            PREF(B, (ip + 8), (wp + 1024), xs, xrow, XSEC)
            ip += 16; wp += 2048;
            #pragma unroll 1
            for (int j = 0; j < 6; ++j) {
                const int F = Fbeg + j;
                const int gend = off1[F + 1];
                f32x4 ca = {0.f,0.f,0.f,0.f}, cb = ca, cc = ca, cd = ca;
                while (s < gend) { PAIRSTEP(ip, wp, xs, xrow, XSEC) }
                const float bias = pb1[F * 16 + l15];
                const int hcol = (F - chunk * 96) * 16 + l15;
                #pragma unroll
                for (int r = 0; r < 4; ++r) {      // D: col=l15, row=lg*4+r
                    hs[(lg * 4 + r) * HP + hcol] = f2bs(gelu_fast(ca[r] + cb[r] + bias));
                    hs[HSEC + (lg * 4 + r) * HP + hcol] = f2bs(gelu_fast(cc[r] + cd[r] + bias));
                }
            }
        }
        __syncthreads();

        // ---------- fc2: linear stream over the wave's 3 groups ----------
        {
            const int Pbeg = chunk * ND16 + wave * 3;
            int s = off2[Pbeg];
            const ushort_t* ip = idx2s + s;
            const ushort_t* wp = w2s + (long)s * 128 + lofs;
            short8 Aa0, Aa1, Aa2, Aa3, Aw0, Aw1, Ba0, Ba1, Ba2, Ba3, Bw0, Bw1;
            PREF(A, ip, wp, hs, hrow, HSEC)
            PREF(B, (ip + 8), (wp + 1024), hs, hrow, HSEC)
            ip += 16; wp += 2048;
#define FC2G(J)                                                          \
            {                                                            \
                const int gend = off2[Pbeg + (J) + 1];                   \
                f32x4 ca = acc0[J], cc = acc1[J];                        \
                f32x4 cb = {0.f,0.f,0.f,0.f}, cd = cb;                   \
                while (s < gend) { PAIRSTEP(ip, wp, hs, hrow, HSEC) }    \
                acc0[J] = ca + cb; acc1[J] = cc + cd;                    \
            }
            FC2G(0) FC2G(1) FC2G(2)
#undef FC2G
        }
        __syncthreads();
    }

    // ---- epilogue: acc -> LDS (f32) -> coalesced float4 stores ----
    float* sacc = (float*)hs;                       // [32][772] = 98,816 B
    #pragma unroll
    for (int j = 0; j < 3; ++j) {
        const int d = (wave * 3 + j) * 16 + l15;
        #pragma unroll
        for (int r = 0; r < 4; ++r) {
            sacc[(lg * 4 + r) * 772 + d] = acc0[j][r];
            sacc[(16 + lg * 4 + r) * 772 + d] = acc1[j][r];
        }
    }
    __syncthreads();
    {
        const float4* pb24 = (const float4*)pb2;
        #pragma unroll
        for (int i = 0; i < 6; ++i) {
            int e = tid + i * NT;                   // 32 rows x 192 float4
            int row = e / 192, c4 = e % 192;
            float4 v = *(const float4*)&sacc[row * 772 + c4 * 4];
            float4 b = pb24[c4];
            v.x += b.x; v.y += b.y; v.z += b.z; v.w += b.w;
            *(float4*)&out[(rowBase + row) * DIM + c4 * 4] = v;
        }
    }
}

extern "C" void kernel_launch(void* const* d_in, const int* in_sizes, int n_in,
                              void* d_out, int out_size, void* d_ws, size_t ws_size,
                              hipStream_t stream) {
    const float* x = (const float*)d_in[0];
    const float* W1 = (const float*)d_in[1];
    const float* b1 = (const float*)d_in[2];
    const float* W2 = (const float*)d_in[3];
    const float* b2 = (const float*)d_in[4];
    const int* mask1 = (const int*)d_in[5];   // [384,96] int32 0/1
    const int* mask2 = (const int*)d_in[6];   // [96,384]
    float* out = (float*)d_out;

    // ws layout: w1s | w2s | idx1s | idx2s | off1[193] | off2[97]  (~9.5 MiB)
    ushort_t* w1s = (ushort_t*)d_ws;
    ushort_t* w2s = w1s + W1S_TOT;
    ushort_t* idx1s = w2s + W2S_TOT;
    ushort_t* idx2s = idx1s + S1CAP;
    int* off1 = (int*)(idx2s + S2CAP);
    int* off2 = off1 + (NF16 + 1);

    prep_count<<<NF16 + ND16, 64, 0, stream>>>(mask1, mask2, off1, off2);
    prep_scan<<<1, 64, 0, stream>>>(off1, off2, idx1s, idx2s);
    prep_gather<<<NF16 + 2 * ND16, 256, 0, stream>>>(
        W1, W2, mask1, mask2, off1, off2,
        (__hip_bfloat16*)w1s, (__hip_bfloat16*)w2s, idx1s, idx2s);

    const int rows = in_sizes[0] / DIM;        // 36928
    const int nblk = rows / MR;                // 1154
    bsffn_main<<<nblk, NT, 0, stream>>>(
        x, b1, b2, w1s, w2s, idx1s, idx2s, off1, off2, out);
}